// Round 2
// baseline (1880.476 us; speedup 1.0000x reference)
//
#include <hip/hip_runtime.h>
#include <hip/hip_bf16.h>
#include <math.h>

#define N_MEM 300000
#define D     640
#define WAY   5
#define SHOT  5
#define NQ    75      // 15 * 5 query rows
#define K     16      // AUGMENT
#define MEMW  0.2f
#define INV_TEMP (1.0f / 64.0f)

// ws layout (in floats); total ~1,503,472 floats ~= 6.02 MB
#define SBAR_OFF   0                         // 5*640 = 3200
#define SIMSUP_OFF 3200                      // 25
#define SIMMEM_OFF 3232                      // 5*300000 = 1,500,000
#define TOPV_OFF   (SIMMEM_OFF + WAY*N_MEM)  // 80 floats
#define TOPI_OFF   (TOPV_OFF + WAY*K)        // 80 ints

__device__ __forceinline__ float d4(float4 a, float4 b) {
    return a.x*b.x + a.y*b.y + a.z*b.z + a.w*b.w;
}

// ---------------- kernel 1: support prep (1 block, 256 thr) ----------------
// support layout: [shot=5][way=5][640]
__global__ __launch_bounds__(256) void k_prep(const float* __restrict__ support,
                                              float* __restrict__ ws) {
    __shared__ float inv_norm[SHOT * WAY];    // indexed s*WAY + w
    __shared__ float sbar_s[WAY][D];
    int tid  = threadIdx.x;
    int lane = tid & 63;
    int wv   = tid >> 6;

    // 25 support-row inverse norms
    for (int p = wv; p < SHOT * WAY; p += 4) {
        const float* row = support + p * D;
        float ss = 0.f;
        for (int i = lane; i < D; i += 64) { float v = row[i]; ss += v * v; }
        #pragma unroll
        for (int m = 32; m; m >>= 1) ss += __shfl_xor(ss, m);
        if (lane == 0) inv_norm[p] = 1.0f / fmaxf(sqrtf(ss), 1e-12f);
    }
    __syncthreads();

    // sbar[w][d] = (1/5) * sum_s sup_n[w][s][d]
    for (int i = tid; i < WAY * D; i += 256) {
        int w = i / D, d = i % D;
        float acc = 0.f;
        #pragma unroll
        for (int s = 0; s < SHOT; ++s)
            acc += support[(s * WAY + w) * D + d] * inv_norm[s * WAY + w];
        acc *= 0.2f;   // 1/SHOT
        sbar_s[w][d] = acc;
        ws[SBAR_OFF + i] = acc;
    }
    __syncthreads();

    // sim_sup[w][t] = dot(sbar[w], sup_n[w][t])
    for (int p = wv; p < WAY * SHOT; p += 4) {
        int w = p / SHOT, t = p % SHOT;
        const float* row = support + (t * WAY + w) * D;
        float acc = 0.f;
        for (int i = lane; i < D; i += 64) acc += sbar_s[w][i] * row[i];
        #pragma unroll
        for (int m = 32; m; m >>= 1) acc += __shfl_xor(acc, m);
        if (lane == 0) ws[SIMSUP_OFF + w * SHOT + t] = acc * inv_norm[t * WAY + w];
    }
}

// ---------------- kernel 2: memory similarity (HBM-bound) ----------------
// one wave per memory row; sbar fragments kept in registers
__global__ __launch_bounds__(256) void k_sim(const float* __restrict__ memory,
                                             const float* __restrict__ sbar,
                                             float* __restrict__ simmem) {
    int tid   = threadIdx.x;
    int lane  = tid & 63;
    int gwave = blockIdx.x * 4 + (tid >> 6);
    int nwav  = gridDim.x * 4;

    int i0 = lane, i1 = lane + 64, i2 = lane + 128;   // float4 indices (160/row)
    bool has2 = (lane < 32);

    float4 sb[WAY][3];
    #pragma unroll
    for (int w = 0; w < WAY; ++w) {
        const float4* sp = (const float4*)(sbar + w * D);
        sb[w][0] = sp[i0];
        sb[w][1] = sp[i1];
        sb[w][2] = has2 ? sp[i2] : make_float4(0.f, 0.f, 0.f, 0.f);
    }

    for (int m = gwave; m < N_MEM; m += nwav) {
        const float4* row = (const float4*)(memory + (size_t)m * D);
        float4 r0 = row[i0];
        float4 r1 = row[i1];
        float4 r2 = has2 ? row[i2] : make_float4(0.f, 0.f, 0.f, 0.f);

        float ss = d4(r0, r0) + d4(r1, r1) + d4(r2, r2);
        float dw[WAY];
        #pragma unroll
        for (int w = 0; w < WAY; ++w)
            dw[w] = d4(r0, sb[w][0]) + d4(r1, sb[w][1]) + d4(r2, sb[w][2]);

        #pragma unroll
        for (int msk = 32; msk; msk >>= 1) {
            ss += __shfl_xor(ss, msk);
            #pragma unroll
            for (int w = 0; w < WAY; ++w) dw[w] += __shfl_xor(dw[w], msk);
        }
        if (lane == 0) {
            float inv = MEMW / fmaxf(sqrtf(ss), 1e-12f);
            #pragma unroll
            for (int w = 0; w < WAY; ++w)
                simmem[(size_t)w * N_MEM + m] = dw[w] * inv;
        }
    }
}

// ---------------- kernel 3: top-16 per way (5 blocks) ----------------
__global__ __launch_bounds__(256) void k_topk(const float* __restrict__ ws,
                                              float* __restrict__ topv,
                                              int* __restrict__ topi) {
    __shared__ float pv[K * 256];
    __shared__ int   pi[K * 256];
    __shared__ float rv[256];
    __shared__ int   ri[256];
    int w   = blockIdx.x;
    int tid = threadIdx.x;
    const float* simsup = ws + SIMSUP_OFF + w * SHOT;
    const float* simmem = ws + SIMMEM_OFF + (size_t)w * N_MEM;

    for (int k = 0; k < K; ++k) { pv[k * 256 + tid] = -INFINITY; pi[k * 256 + tid] = 0x7fffffff; }

    float vmin = -INFINITY; int minslot = 0;
    const int total = N_MEM + SHOT;
    for (int i = tid; i < total; i += 256) {
        float v = (i < SHOT) ? simsup[i] : simmem[i - SHOT];
        if (v > vmin) {
            pv[minslot * 256 + tid] = v;
            pi[minslot * 256 + tid] = i;
            vmin = pv[tid]; minslot = 0;
            #pragma unroll
            for (int k = 1; k < K; ++k) {
                float x = pv[k * 256 + tid];
                if (x < vmin) { vmin = x; minslot = k; }
            }
        }
    }
    __syncthreads();

    // 16 rounds of block-wide argmax (tie-break: lower candidate index)
    for (int r = 0; r < K; ++r) {
        float bv = -INFINITY; int bi = 0x7fffffff; int bslot = -1;
        #pragma unroll
        for (int k = 0; k < K; ++k) {
            float v = pv[k * 256 + tid]; int idx = pi[k * 256 + tid];
            if (v > bv || (v == bv && idx < bi)) { bv = v; bi = idx; bslot = k; }
        }
        rv[tid] = bv; ri[tid] = bi;
        __syncthreads();
        for (int s = 128; s; s >>= 1) {
            if (tid < s) {
                float v2 = rv[tid + s]; int i2 = ri[tid + s];
                if (v2 > rv[tid] || (v2 == rv[tid] && i2 < ri[tid])) { rv[tid] = v2; ri[tid] = i2; }
            }
            __syncthreads();
        }
        float winv = rv[0]; int wini = ri[0];
        if (tid == 0) { topv[w * K + r] = winv; topi[w * K + r] = wini; }
        if (bslot >= 0 && bi == wini) {
            pv[bslot * 256 + tid] = -INFINITY;
            pi[bslot * 256 + tid] = 0x7fffffff;
        }
        __syncthreads();
    }
}

// ---------------- kernel 4: prototypes + logits (1 block) ----------------
__global__ __launch_bounds__(256) void k_final(const float* __restrict__ support,
                                               const float* __restrict__ query,
                                               const float* __restrict__ memory,
                                               const float* __restrict__ topv,
                                               const int* __restrict__ topi,
                                               float* __restrict__ out) {
    __shared__ float proto_s[WAY][D];
    __shared__ float inv_n[WAY];
    int tid = threadIdx.x;

    // proto[w][d] = sum_k v_k * emb_k[d] / sum_k v_k   (emb = RAW rows)
    for (int i = tid; i < WAY * D; i += 256) {
        int w = i / D, d = i % D;
        float acc = 0.f, s = 0.f;
        #pragma unroll
        for (int k = 0; k < K; ++k) {
            float v = topv[w * K + k];
            int idx = topi[w * K + k];
            const float* emb = (idx < SHOT) ? (support + (idx * WAY + w) * D)
                                            : (memory + (size_t)(idx - SHOT) * D);
            acc += v * emb[d];
            s += v;
        }
        proto_s[w][d] = acc / s;
    }
    __syncthreads();

    int lane = tid & 63, wv = tid >> 6;
    for (int w = wv; w < WAY; w += 4) {
        float ss = 0.f;
        for (int i = lane; i < D; i += 64) { float v = proto_s[w][i]; ss += v * v; }
        #pragma unroll
        for (int m = 32; m; m >>= 1) ss += __shfl_xor(ss, m);
        if (lane == 0) inv_n[w] = 1.0f / fmaxf(sqrtf(ss), 1e-12f);
    }
    __syncthreads();

    // logits[q][w] = dot(query[q], proto_n[w]) / 64
    for (int o = tid; o < NQ * WAY; o += 256) {
        int q = o / WAY, w = o % WAY;
        const float* qr = query + q * D;
        float acc = 0.f;
        for (int d = 0; d < D; ++d) acc += qr[d] * proto_s[w][d];
        out[o] = acc * inv_n[w] * INV_TEMP;
    }
}

extern "C" void kernel_launch(void* const* d_in, const int* in_sizes, int n_in,
                              void* d_out, int out_size, void* d_ws, size_t ws_size,
                              hipStream_t stream) {
    const float* support = (const float*)d_in[0];   // [1,5,5,640]
    const float* query   = (const float*)d_in[1];   // [1,15,5,640]
    const float* memory  = (const float*)d_in[2];   // [300000,640]
    float* ws  = (float*)d_ws;                      // needs ~6.03 MB
    float* out = (float*)d_out;                     // [75,5] fp32

    hipLaunchKernelGGL(k_prep, dim3(1), dim3(256), 0, stream, support, ws);
    hipLaunchKernelGGL(k_sim,  dim3(2048), dim3(256), 0, stream,
                       memory, ws + SBAR_OFF, ws + SIMMEM_OFF);
    hipLaunchKernelGGL(k_topk, dim3(WAY), dim3(256), 0, stream,
                       ws, ws + TOPV_OFF, (int*)(ws + TOPI_OFF));
    hipLaunchKernelGGL(k_final, dim3(1), dim3(256), 0, stream,
                       support, query, memory,
                       ws + TOPV_OFF, (const int*)(ws + TOPI_OFF), out);
}